// Round 2
// baseline (475.110 us; speedup 1.0000x reference)
//
#include <hip/hip_runtime.h>
#include <hip/hip_bf16.h>
#include <stdint.h>

// ---------------------------------------------------------------------------
// MatryoshkaAttention: B=2, T=4096, D=1024, active_dim=512 -> H=8, hd=64.
// fp32 in/out (sniffed on-device), bf16 MFMA compute.
// R13: flatten the causal triangle. Flash work is split into uniform chunks
// of <=16 K-tiles (NW=5120 partials, avg 13 steps, max 16 -- was max 32),
// mapped by closed-form prefix sums (no tables). Combine sums 1..4 partials
// per unit. V loads issued at step start (~800cy cover). Copy-free K
// ping-pong (kr[nt&1] static slots).
// NO launch_bounds min arg anywhere (R6/R8: forcing VGPR caps below footprint
// -> scratch spill, ~0.7-1 GB HBM traffic).
// ---------------------------------------------------------------------------

typedef __bf16 bf16;
typedef bf16  bf16x8 __attribute__((ext_vector_type(8)));
typedef bf16  bf16x4v __attribute__((ext_vector_type(4)));
typedef float f32x4  __attribute__((ext_vector_type(4)));
typedef uint32_t u32x4 __attribute__((ext_vector_type(4)));

#define SCL 0.18033688011112042f   /* 0.125 * log2(e): p = 2^(s*SCL) = e^(s/8) */
#define NEG_BIG (-30000.0f)

// chunking of the causal triangle (per bh):
//   ntiles(p) = (p>>1)+1   (64-col K tiles for q-band p of 32 rows)
//   nch(p)    = ceil(ntiles/16) = (p>>5)+1 when written via q below
//   off(p)    = closed-form prefix sum; off(128) = 320 chunks per bh
#define NSUB 320
#define NW   (16 * NSUB)   /* 5120 partial wids */

static __device__ __forceinline__ int off_p(int p) {
    const int t = p >> 1, q = t >> 4, r = t & 15;
    return 2 * (8 * q * (q + 1) + r * (q + 1)) + (p & 1) * (q + 1);
}

static __device__ __forceinline__ f32x4 mfma_bf16(bf16x8 a, bf16x8 b, f32x4 c) {
    return __builtin_amdgcn_mfma_f32_16x16x32_bf16(a, b, c, 0, 0, 0);
}

// ---------------------------------------------------------------------------
__global__ __launch_bounds__(256) void sniff_dtype(
    const uint16_t* __restrict__ x, int* __restrict__ flag)
{
    __shared__ int cnt;
    if (threadIdx.x == 0) cnt = 0;
    __syncthreads();
    int local = 0;
    for (int i = threadIdx.x; i < 2048; i += 256) {
        const int e = (x[i] >> 7) & 0xFF;
        if (e >= 0xC0) ++local;
    }
    if (local) atomicAdd(&cnt, local);
    __syncthreads();
    if (threadIdx.x == 0) *flag = (cnt >= 8) ? 1 : 0;
}

// ---------------------------------------------------------------------------
// One launch converts all five tensors (cols 0..511 of [rows][1024]) into
// packed bf16. Blocks 0..2047: x -> xb. Blocks 2048..2559: weights -> wb.
// ---------------------------------------------------------------------------
__global__ __launch_bounds__(256) void convert_all(
    const void* __restrict__ x,
    const void* __restrict__ wq, const void* __restrict__ wk,
    const void* __restrict__ wv, const void* __restrict__ wo,
    bf16* __restrict__ xb, bf16* __restrict__ wb,
    const int* __restrict__ flag)
{
    const int bid = blockIdx.x;
    const void* src;
    bf16* dst;
    int sub;
    if (bid < 2048) { src = x; dst = xb; sub = bid; }
    else {
        const int w = bid - 2048;
        const int wsel = w >> 7;
        src = (wsel == 0) ? wq : (wsel == 1) ? wk : (wsel == 2) ? wv : wo;
        dst = wb + (size_t)wsel * 262144;
        sub = w & 127;
    }
    const int i = (sub * 256 + threadIdx.x) * 8;
    const int r = i >> 9, c = i & 511;
    bf16x8 v;
    if (*flag) {
        const float* s = (const float*)src + (size_t)r * 1024 + c;
        f32x4 f0 = *(const f32x4*)s;
        f32x4 f1 = *(const f32x4*)(s + 4);
#pragma unroll
        for (int j = 0; j < 4; ++j) { v[j] = (bf16)f0[j]; v[4 + j] = (bf16)f1[j]; }
    } else {
        v = *(const bf16x8*)((const bf16*)src + (size_t)r * 1024 + c);
    }
    *(bf16x8*)(dst + (size_t)r * 512 + c) = v;
}

// ---------------------------------------------------------------------------
// Fused QKV NT GEMM with register ping-pong prefetch.
// A:[8192][512]; B:[1536][512] = wq|wk|wv contiguous.
// sel 0=Q head layout (pre-scaled by SCL), 1=K head layout,
// sel 2=V transposed (LDS transpose).
// ---------------------------------------------------------------------------
struct GF { bf16x8 a; bf16x8 b[4]; };

__global__ __launch_bounds__(256) void gemm_qkv(
    const bf16* __restrict__ A, const bf16* __restrict__ B,
    bf16* __restrict__ Qb, bf16* __restrict__ Kb, bf16* __restrict__ Vb)
{
    const int n0   = blockIdx.x * 64;
    const int m0   = blockIdx.y * 64;
    const int wave = threadIdx.x >> 6;
    const int lane = threadIdx.x & 63;
    const int col  = lane & 15;
    const int quad = lane >> 4;

    const bf16* __restrict__ Ar = A + (size_t)(m0 + wave * 16 + col) * 512 + quad * 8;
    const bf16* __restrict__ Br = B + (size_t)(n0 + col) * 512 + quad * 8;

    f32x4 acc[4];
#pragma unroll
    for (int nt = 0; nt < 4; ++nt)
#pragma unroll
        for (int r = 0; r < 4; ++r) acc[nt][r] = 0.0f;

    auto load_f = [&](int k0, GF& f) {
        f.a = *(const bf16x8*)(Ar + k0);
#pragma unroll
        for (int nt = 0; nt < 4; ++nt)
            f.b[nt] = *(const bf16x8*)(Br + (size_t)(nt * 16) * 512 + k0);
    };
    auto do_mfma = [&](const GF& f) {
#pragma unroll
        for (int nt = 0; nt < 4; ++nt)
            acc[nt] = mfma_bf16(f.a, f.b[nt], acc[nt]);
    };

    GF f0, f1;
    load_f(0, f0);
#pragma unroll
    for (int k0 = 0; k0 < 512; k0 += 64) {
        if (k0 + 32 < 512) load_f(k0 + 32, f1);
        do_mfma(f0);
        if (k0 + 64 < 512) load_f(k0 + 64, f0);
        do_mfma(f1);
    }

    const int sel = n0 >> 9;
    const int bb  = m0 >> 12;

    if (sel < 2) {
        bf16* __restrict__ dst = (sel == 0) ? Qb : Kb;
        const float qs = (sel == 0) ? SCL : 1.0f;   // fold softmax scale into Q
#pragma unroll
        for (int nt = 0; nt < 4; ++nt) {
#pragma unroll
            for (int r = 0; r < 4; ++r) {
                const int row = m0 + wave * 16 + quad * 4 + r;
                const int cn  = (n0 & 511) + nt * 16 + col;
                const int t = row & 4095;
                const int h = cn >> 6, d = cn & 63;
                dst[((size_t)(bb * 8 + h) * 4096 + t) * 64 + d] = (bf16)(acc[nt][r] * qs);
            }
        }
    } else {
        __shared__ __align__(16) bf16 T[64][72];
#pragma unroll
        for (int nt = 0; nt < 4; ++nt)
#pragma unroll
            for (int r = 0; r < 4; ++r)
                T[wave * 16 + quad * 4 + r][nt * 16 + col] = (bf16)acc[nt][r];
        __syncthreads();

        const int h0 = (n0 - 1024) >> 6;
        const int d  = threadIdx.x >> 2;
        const int tp = (threadIdx.x & 3) * 16;
        bf16 vals[16];
#pragma unroll
        for (int i = 0; i < 16; ++i) vals[i] = T[tp + i][d];
        bf16* dst = Vb + ((size_t)(bb * 8 + h0) * 64 + d) * 4096 + (m0 & 4095) + tp;
        *(bf16x8*)dst       = *(bf16x8*)&vals[0];
        *(bf16x8*)(dst + 8) = *(bf16x8*)&vals[8];
    }
}

// ---------------------------------------------------------------------------
// Out-projection NT GEMM + fused pad, with ping-pong prefetch.
// grid (16,128). n0<512: C = A*wo^T; n0>=512: zero-fill tile.
// ---------------------------------------------------------------------------
__global__ __launch_bounds__(256) void gemm_out_pad(
    const bf16* __restrict__ A, const bf16* __restrict__ B, void* __restrict__ C,
    const int* __restrict__ flag)
{
    const int n0   = blockIdx.x * 64;
    const int m0   = blockIdx.y * 64;
    const int isf  = *flag;

    if (n0 >= 512) {
        const int row = m0 + (threadIdx.x >> 2);
        const int c0  = n0 + (threadIdx.x & 3) * 16;
        if (isf) {
            float* p = (float*)C + (size_t)row * 1024 + c0;
            f32x4 z; z[0] = 0.f; z[1] = 0.f; z[2] = 0.f; z[3] = 0.f;
#pragma unroll
            for (int j = 0; j < 4; ++j) *(f32x4*)(p + j * 4) = z;
        } else {
            bf16* p = (bf16*)C + (size_t)row * 1024 + c0;
            u32x4 z; z[0] = 0u; z[1] = 0u; z[2] = 0u; z[3] = 0u;
            *(u32x4*)p = z; *(u32x4*)(p + 8) = z;
        }
        return;
    }

    const int wave = threadIdx.x >> 6;
    const int lane = threadIdx.x & 63;
    const int col  = lane & 15;
    const int quad = lane >> 4;

    const bf16* __restrict__ Ar = A + (size_t)(m0 + wave * 16 + col) * 512 + quad * 8;
    const bf16* __restrict__ Br = B + (size_t)(n0 + col) * 512 + quad * 8;

    f32x4 acc[4];
#pragma unroll
    for (int nt = 0; nt < 4; ++nt)
#pragma unroll
        for (int r = 0; r < 4; ++r) acc[nt][r] = 0.0f;

    auto load_f = [&](int k0, GF& f) {
        f.a = *(const bf16x8*)(Ar + k0);
#pragma unroll
        for (int nt = 0; nt < 4; ++nt)
            f.b[nt] = *(const bf16x8*)(Br + (size_t)(nt * 16) * 512 + k0);
    };
    auto do_mfma = [&](const GF& f) {
#pragma unroll
        for (int nt = 0; nt < 4; ++nt)
            acc[nt] = mfma_bf16(f.a, f.b[nt], acc[nt]);
    };

    GF f0, f1;
    load_f(0, f0);
#pragma unroll
    for (int k0 = 0; k0 < 512; k0 += 64) {
        if (k0 + 32 < 512) load_f(k0 + 32, f1);
        do_mfma(f0);
        if (k0 + 64 < 512) load_f(k0 + 64, f0);
        do_mfma(f1);
    }

#pragma unroll
    for (int nt = 0; nt < 4; ++nt) {
#pragma unroll
        for (int r = 0; r < 4; ++r) {
            const int row = m0 + wave * 16 + quad * 4 + r;
            const int cn  = n0 + nt * 16 + col;
            const float f = acc[nt][r];
            if (isf) ((float*)C)[(size_t)row * 1024 + cn] = f;
            else     ((bf16*)C)[(size_t)row * 1024 + cn] = (bf16)f;
        }
    }
}

// ---------------------------------------------------------------------------
// Flash causal attention, chunked: each wid handles one <=16-tile chunk of
// one (bh, q-band) unit. S^T operand swap, 2 strips (32 q rows) per wid.
// Q pre-scaled by SCL. V loads at step start; K ping-pong kr[nt&1].
// Partial index pw = bh*320 + sub, sub = off(p)+c.
// ---------------------------------------------------------------------------
__global__ __launch_bounds__(256) void flash_kernel(
    const bf16* __restrict__ Q, const bf16* __restrict__ K,
    const bf16* __restrict__ Vt,
    float* __restrict__ Opart, float* __restrict__ Spart)
{
    const int wave = threadIdx.x >> 6;
    const int wid  = blockIdx.x * 4 + wave;     // 0..5119
    const int bh   = wid & 15;
    const int sub  = (NSUB - 1) - (wid >> 4);   // heavy q-bands first
    // binary search p: largest p with off(p) <= sub
    int lo = 0, hi = 127;
    while (lo < hi) {
        const int mid = (lo + hi + 1) >> 1;
        if (off_p(mid) <= sub) lo = mid; else hi = mid - 1;
    }
    const int p = lo;
    const int c = sub - off_p(p);

    const int lane = threadIdx.x & 63;
    const int qc   = lane & 15;
    const int quad = lane >> 4;

    const bf16* __restrict__ Qh = Q  + (size_t)bh * (4096 * 64);
    const bf16* __restrict__ Kh = K  + (size_t)bh * (4096 * 64);
    const bf16* __restrict__ Vh = Vt + (size_t)bh * (64 * 4096);

    const int qrowA  = p * 32;
    const int ktmax  = p >> 1;                  // last (diag) K-tile index
    const int ntiles = ktmax + 1;
    const int k0t    = c * 16;
    const int k1t    = (k0t + 16 < ntiles) ? (k0t + 16) : ntiles;

    bf16x8 aqA0 = *(const bf16x8*)(Qh + (size_t)(qrowA + qc) * 64 + quad * 8);
    bf16x8 aqA1 = *(const bf16x8*)(Qh + (size_t)(qrowA + qc) * 64 + 32 + quad * 8);
    bf16x8 aqB0 = *(const bf16x8*)(Qh + (size_t)(qrowA + 16 + qc) * 64 + quad * 8);
    bf16x8 aqB1 = *(const bf16x8*)(Qh + (size_t)(qrowA + 16 + qc) * 64 + 32 + quad * 8);

    f32x4 oA[4], oB[4];
    f32x4 s4A, s4B;
#pragma unroll
    for (int r = 0; r < 4; ++r) { s4A[r] = 0.f; s4B[r] = 0.f; }
#pragma unroll
    for (int nt = 0; nt < 4; ++nt)
#pragma unroll
        for (int r = 0; r < 4; ++r) { oA[nt][r] = 0.f; oB[nt][r] = 0.f; }

    __shared__ __align__(16) bf16 Plds[4][2][16][72];  // per-wave, no barriers
    bf16* myPA = &Plds[wave][0][0][0];
    bf16* myPB = &Plds[wave][1][0][0];

    auto load_knt = [&](int kb, int nt, bf16x8 (&kf)[2]) {
        const bf16* kp = Kh + (size_t)(kb * 64 + nt * 16 + qc) * 64 + quad * 8;
        kf[0] = *(const bf16x8*)kp;
        kf[1] = *(const bf16x8*)(kp + 32);
    };

    bf16x8 kr[2][2];
    load_knt(k0t, 0, kr[0]);

    for (int kb = k0t; kb < k1t; ++kb) {
        const int kbase = kb * 64;
        const bool diag = (kb == ktmax);

        // ---- V loads for the whole step at step start (~800cy cover) ----
        bf16x8 vv[4][2];
#pragma unroll
        for (int nt = 0; nt < 4; ++nt) {
            const bf16* vp = Vh + (size_t)(nt * 16 + qc) * 4096 + kbase + quad * 8;
            vv[nt][0] = *(const bf16x8*)vp;
            vv[nt][1] = *(const bf16x8*)(vp + 32);
        }

#pragma unroll
        for (int nt = 0; nt < 4; ++nt) {
            // prefetch next K fragment into the other slot (static kr[nt&1])
            if (nt < 3)            load_knt(kb, nt + 1, kr[(nt + 1) & 1]);
            else if (kb + 1 < k1t) load_knt(kb + 1, 0, kr[0]);
            const bf16x8* kc = kr[nt & 1];

            // QK^T (S^T layout), both strips share the K fragment
            f32x4 sA; sA[0] = 0.f; sA[1] = 0.f; sA[2] = 0.f; sA[3] = 0.f;
            sA = mfma_bf16(kc[0], aqA0, sA);
            sA = mfma_bf16(kc[1], aqA1, sA);
            f32x4 sB; sB[0] = 0.f; sB[1] = 0.f; sB[2] = 0.f; sB[3] = 0.f;
            sB = mfma_bf16(kc[0], aqB0, sB);
            sB = mfma_bf16(kc[1], aqB1, sB);

            bf16x4v pkA, pkB;
#pragma unroll
            for (int r = 0; r < 4; ++r) {
                float vA = sA[r];           // Q pre-scaled: no mul here
                float vB = sB[r];
                if (diag) {
                    const int kg = kbase + nt * 16 + quad * 4 + r;
                    if (kg > qrowA + qc)      vA = NEG_BIG;
                    if (kg > qrowA + 16 + qc) vB = NEG_BIG;
                }
                const float pA = __builtin_amdgcn_exp2f(vA);
                const float pB = __builtin_amdgcn_exp2f(vB);
                s4A[r] += pA;
                s4B[r] += pB;
                pkA[r] = (bf16)pA;
                pkB[r] = (bf16)pB;
            }
            *(bf16x4v*)(myPA + qc * 72 + nt * 16 + quad * 4) = pkA;
            *(bf16x4v*)(myPB + qc * 72 + nt * 16 + quad * 4) = pkB;
        }

        // ---- PV for both strips (shared V frags) ----
#pragma unroll
        for (int ks = 0; ks < 2; ++ks) {
            bf16x8 apA = *(const bf16x8*)(myPA + qc * 72 + ks * 32 + quad * 8);
            bf16x8 apB = *(const bf16x8*)(myPB + qc * 72 + ks * 32 + quad * 8);
#pragma unroll
            for (int nt = 0; nt < 4; ++nt) {
                oA[nt] = mfma_bf16(apA, vv[nt][ks], oA[nt]);
                oB[nt] = mfma_bf16(apB, vv[nt][ks], oB[nt]);
            }
        }
    }

    float sumA = (s4A[0] + s4A[1]) + (s4A[2] + s4A[3]);
    float sumB = (s4B[0] + s4B[1]) + (s4B[2] + s4B[3]);
    sumA += __shfl_xor(sumA, 16, 64);
    sumA += __shfl_xor(sumA, 32, 64);
    sumB += __shfl_xor(sumB, 16, 64);
    sumB += __shfl_xor(sumB, 32, 64);

    const int pw = bh * NSUB + sub;
    float* op = Opart + (size_t)pw * 2048;
#pragma unroll
    for (int nt = 0; nt < 4; ++nt)
#pragma unroll
        for (int r = 0; r < 4; ++r) {
            op[(quad * 4 + r) * 64 + nt * 16 + qc]        = oA[nt][r];
            op[1024 + (quad * 4 + r) * 64 + nt * 16 + qc] = oB[nt][r];
        }
    if (quad == 0) {
        float* sp = Spart + (size_t)pw * 32;
        sp[qc]      = sumA;
        sp[16 + qc] = sumB;
    }
}

// ---------------------------------------------------------------------------
// Combine: 4 units/block (grid 512, 256 thr). Unit u=(p,bh) sums its 1..4
// chunk partials (closed-form base/nch) and normalizes.
// ---------------------------------------------------------------------------
__global__ __launch_bounds__(256) void combine_kernel(
    const float* __restrict__ Opart, const float* __restrict__ Spart,
    bf16* __restrict__ Ob)
{
    const int u  = blockIdx.x * 4 + (threadIdx.x >> 6);  // 0..2047
    const int p  = u >> 4;
    const int bh = u & 15;
    const int cc = threadIdx.x & 63;
    const int b = bh >> 3, h = bh & 7;

    const int base = bh * NSUB + off_p(p);
    const int nch  = ((p >> 1) >> 4) + 1;     // ceil(ntiles/16)

    const float* o0 = Opart + (size_t)base * 2048;
    const float* s0 = Spart + (size_t)base * 32;

#pragma unroll
    for (int X = 0; X < 2; ++X) {
        for (int r = 0; r < 16; ++r) {
            float ssum = 0.f, osum = 0.f;
            for (int s = 0; s < nch; ++s) {
                ssum += s0[s * 32 + X * 16 + r];
                osum += o0[(size_t)s * 2048 + X * 1024 + r * 64 + cc];
            }
            const float v = osum / ssum;
            const int t = p * 32 + X * 16 + r;
            Ob[((size_t)b * 4096 + t) * 512 + h * 64 + cc] = (bf16)v;
        }
    }
}

extern "C" void kernel_launch(void* const* d_in, const int* in_sizes, int n_in,
                              void* d_out, int out_size, void* d_ws, size_t ws_size,
                              hipStream_t stream)
{
    (void)in_sizes; (void)n_in; (void)out_size; (void)ws_size;
    const void* x  = d_in[0];
    const void* wq = d_in[1];
    const void* wk = d_in[2];
    const void* wv = d_in[3];
    const void* wo = d_in[4];

    char* wsb = (char*)d_ws;
    bf16* xb   = (bf16*)(wsb + 0);          // [8192][512] (aliased by Ob)
    bf16* Ob   = (bf16*)(wsb + 0);
    bf16* wb   = (bf16*)(wsb + 8388608);    // [2048][512]: wq|wk|wv|wo
    bf16* wob  = wb + 3 * 262144;
    bf16* Qb   = (bf16*)(wsb + 10485760);   // [2][8][4096][64]
    bf16* Kb   = (bf16*)(wsb + 18874368);
    bf16* Vb   = (bf16*)(wsb + 27262976);   // [2][8][64][4096]
    int*  flag = (int*) (wsb + 35651584);
    float* Opart = (float*)(wsb + 35651712);   // [5120][2][16][64] fp32 = 41.9MB
    float* Spart = (float*)(wsb + 77594752);   // [5120][32] fp32
    // total ws use ~78.3 MB

    const dim3 blk(256);

    sniff_dtype<<<1, blk, 0, stream>>>((const uint16_t*)x, flag);
    convert_all<<<2560, blk, 0, stream>>>(x, wq, wk, wv, wo, xb, wb, flag);

    gemm_qkv<<<dim3(24, 128), blk, 0, stream>>>(xb, wb, Qb, Kb, Vb);

    flash_kernel<<<dim3(NW / 4), blk, 0, stream>>>(Qb, Kb, Vb, Opart, Spart);
    combine_kernel<<<dim3(512), blk, 0, stream>>>(Opart, Spart, Ob);

    gemm_out_pad<<<dim3(16, 128), blk, 0, stream>>>(Ob, wob, d_out, flag);
}

// Round 3
// 413.101 us; speedup vs baseline: 1.1501x; 1.1501x over previous
//
#include <hip/hip_runtime.h>
#include <hip/hip_bf16.h>
#include <stdint.h>

// ---------------------------------------------------------------------------
// MatryoshkaAttention: B=2, T=4096, D=1024, active_dim=512 -> H=8, hd=64.
// fp32 in/out (sniffed on-device), bf16 MFMA compute.
// R14: revert R13 chunking (regressed: cache-locality loss). Flash is
// L2/L3-bandwidth-bound (1.07 GB K/V re-reads vs 16 MB footprint). Fix:
// XCD-partitioned schedule on the proven R12 body -- bid = s*8 + x, so XCD x
// (round-robin dispatch heuristic) handles only heads {2x, 2x+1}: 2 MB K+V
// working set fits the 4 MB per-XCD L2. Block's 4 waves = (2 heads x 2
// halves) of the SAME q-pair; heavy pairs first per XCD.
// NO launch_bounds min arg anywhere (R6/R8: forcing VGPR caps below footprint
// -> scratch spill, ~0.7-1 GB HBM traffic).
// ---------------------------------------------------------------------------

typedef __bf16 bf16;
typedef bf16  bf16x8 __attribute__((ext_vector_type(8)));
typedef bf16  bf16x4v __attribute__((ext_vector_type(4)));
typedef float f32x4  __attribute__((ext_vector_type(4)));
typedef uint32_t u32x4 __attribute__((ext_vector_type(4)));

#define SCL 0.18033688011112042f   /* 0.125 * log2(e): p = 2^(s*SCL) = e^(s/8) */
#define NEG_BIG (-30000.0f)

static __device__ __forceinline__ f32x4 mfma_bf16(bf16x8 a, bf16x8 b, f32x4 c) {
    return __builtin_amdgcn_mfma_f32_16x16x32_bf16(a, b, c, 0, 0, 0);
}

// ---------------------------------------------------------------------------
__global__ __launch_bounds__(256) void sniff_dtype(
    const uint16_t* __restrict__ x, int* __restrict__ flag)
{
    __shared__ int cnt;
    if (threadIdx.x == 0) cnt = 0;
    __syncthreads();
    int local = 0;
    for (int i = threadIdx.x; i < 2048; i += 256) {
        const int e = (x[i] >> 7) & 0xFF;
        if (e >= 0xC0) ++local;
    }
    if (local) atomicAdd(&cnt, local);
    __syncthreads();
    if (threadIdx.x == 0) *flag = (cnt >= 8) ? 1 : 0;
}

// ---------------------------------------------------------------------------
// One launch converts all five tensors (cols 0..511 of [rows][1024]) into
// packed bf16. Blocks 0..2047: x -> xb. Blocks 2048..2559: weights -> wb.
// ---------------------------------------------------------------------------
__global__ __launch_bounds__(256) void convert_all(
    const void* __restrict__ x,
    const void* __restrict__ wq, const void* __restrict__ wk,
    const void* __restrict__ wv, const void* __restrict__ wo,
    bf16* __restrict__ xb, bf16* __restrict__ wb,
    const int* __restrict__ flag)
{
    const int bid = blockIdx.x;
    const void* src;
    bf16* dst;
    int sub;
    if (bid < 2048) { src = x; dst = xb; sub = bid; }
    else {
        const int w = bid - 2048;
        const int wsel = w >> 7;
        src = (wsel == 0) ? wq : (wsel == 1) ? wk : (wsel == 2) ? wv : wo;
        dst = wb + (size_t)wsel * 262144;
        sub = w & 127;
    }
    const int i = (sub * 256 + threadIdx.x) * 8;
    const int r = i >> 9, c = i & 511;
    bf16x8 v;
    if (*flag) {
        const float* s = (const float*)src + (size_t)r * 1024 + c;
        f32x4 f0 = *(const f32x4*)s;
        f32x4 f1 = *(const f32x4*)(s + 4);
#pragma unroll
        for (int j = 0; j < 4; ++j) { v[j] = (bf16)f0[j]; v[4 + j] = (bf16)f1[j]; }
    } else {
        v = *(const bf16x8*)((const bf16*)src + (size_t)r * 1024 + c);
    }
    *(bf16x8*)(dst + (size_t)r * 512 + c) = v;
}

// ---------------------------------------------------------------------------
// Fused QKV NT GEMM with register ping-pong prefetch.
// A:[8192][512]; B:[1536][512] = wq|wk|wv contiguous.
// sel 0=Q head layout (pre-scaled by SCL), 1=K head layout,
// sel 2=V transposed (LDS transpose).
// ---------------------------------------------------------------------------
struct GF { bf16x8 a; bf16x8 b[4]; };

__global__ __launch_bounds__(256) void gemm_qkv(
    const bf16* __restrict__ A, const bf16* __restrict__ B,
    bf16* __restrict__ Qb, bf16* __restrict__ Kb, bf16* __restrict__ Vb)
{
    const int n0   = blockIdx.x * 64;
    const int m0   = blockIdx.y * 64;
    const int wave = threadIdx.x >> 6;
    const int lane = threadIdx.x & 63;
    const int col  = lane & 15;
    const int quad = lane >> 4;

    const bf16* __restrict__ Ar = A + (size_t)(m0 + wave * 16 + col) * 512 + quad * 8;
    const bf16* __restrict__ Br = B + (size_t)(n0 + col) * 512 + quad * 8;

    f32x4 acc[4];
#pragma unroll
    for (int nt = 0; nt < 4; ++nt)
#pragma unroll
        for (int r = 0; r < 4; ++r) acc[nt][r] = 0.0f;

    auto load_f = [&](int k0, GF& f) {
        f.a = *(const bf16x8*)(Ar + k0);
#pragma unroll
        for (int nt = 0; nt < 4; ++nt)
            f.b[nt] = *(const bf16x8*)(Br + (size_t)(nt * 16) * 512 + k0);
    };
    auto do_mfma = [&](const GF& f) {
#pragma unroll
        for (int nt = 0; nt < 4; ++nt)
            acc[nt] = mfma_bf16(f.a, f.b[nt], acc[nt]);
    };

    GF f0, f1;
    load_f(0, f0);
#pragma unroll
    for (int k0 = 0; k0 < 512; k0 += 64) {
        if (k0 + 32 < 512) load_f(k0 + 32, f1);
        do_mfma(f0);
        if (k0 + 64 < 512) load_f(k0 + 64, f0);
        do_mfma(f1);
    }

    const int sel = n0 >> 9;
    const int bb  = m0 >> 12;

    if (sel < 2) {
        bf16* __restrict__ dst = (sel == 0) ? Qb : Kb;
        const float qs = (sel == 0) ? SCL : 1.0f;   // fold softmax scale into Q
#pragma unroll
        for (int nt = 0; nt < 4; ++nt) {
#pragma unroll
            for (int r = 0; r < 4; ++r) {
                const int row = m0 + wave * 16 + quad * 4 + r;
                const int cn  = (n0 & 511) + nt * 16 + col;
                const int t = row & 4095;
                const int h = cn >> 6, d = cn & 63;
                dst[((size_t)(bb * 8 + h) * 4096 + t) * 64 + d] = (bf16)(acc[nt][r] * qs);
            }
        }
    } else {
        __shared__ __align__(16) bf16 T[64][72];
#pragma unroll
        for (int nt = 0; nt < 4; ++nt)
#pragma unroll
            for (int r = 0; r < 4; ++r)
                T[wave * 16 + quad * 4 + r][nt * 16 + col] = (bf16)acc[nt][r];
        __syncthreads();

        const int h0 = (n0 - 1024) >> 6;
        const int d  = threadIdx.x >> 2;
        const int tp = (threadIdx.x & 3) * 16;
        bf16 vals[16];
#pragma unroll
        for (int i = 0; i < 16; ++i) vals[i] = T[tp + i][d];
        bf16* dst = Vb + ((size_t)(bb * 8 + h0) * 64 + d) * 4096 + (m0 & 4095) + tp;
        *(bf16x8*)dst       = *(bf16x8*)&vals[0];
        *(bf16x8*)(dst + 8) = *(bf16x8*)&vals[8];
    }
}

// ---------------------------------------------------------------------------
// Out-projection NT GEMM + fused pad, with ping-pong prefetch.
// grid (16,128). n0<512: C = A*wo^T; n0>=512: zero-fill tile.
// ---------------------------------------------------------------------------
__global__ __launch_bounds__(256) void gemm_out_pad(
    const bf16* __restrict__ A, const bf16* __restrict__ B, void* __restrict__ C,
    const int* __restrict__ flag)
{
    const int n0   = blockIdx.x * 64;
    const int m0   = blockIdx.y * 64;
    const int isf  = *flag;

    if (n0 >= 512) {
        const int row = m0 + (threadIdx.x >> 2);
        const int c0  = n0 + (threadIdx.x & 3) * 16;
        if (isf) {
            float* p = (float*)C + (size_t)row * 1024 + c0;
            f32x4 z; z[0] = 0.f; z[1] = 0.f; z[2] = 0.f; z[3] = 0.f;
#pragma unroll
            for (int j = 0; j < 4; ++j) *(f32x4*)(p + j * 4) = z;
        } else {
            bf16* p = (bf16*)C + (size_t)row * 1024 + c0;
            u32x4 z; z[0] = 0u; z[1] = 0u; z[2] = 0u; z[3] = 0u;
            *(u32x4*)p = z; *(u32x4*)(p + 8) = z;
        }
        return;
    }

    const int wave = threadIdx.x >> 6;
    const int lane = threadIdx.x & 63;
    const int col  = lane & 15;
    const int quad = lane >> 4;

    const bf16* __restrict__ Ar = A + (size_t)(m0 + wave * 16 + col) * 512 + quad * 8;
    const bf16* __restrict__ Br = B + (size_t)(n0 + col) * 512 + quad * 8;

    f32x4 acc[4];
#pragma unroll
    for (int nt = 0; nt < 4; ++nt)
#pragma unroll
        for (int r = 0; r < 4; ++r) acc[nt][r] = 0.0f;

    auto load_f = [&](int k0, GF& f) {
        f.a = *(const bf16x8*)(Ar + k0);
#pragma unroll
        for (int nt = 0; nt < 4; ++nt)
            f.b[nt] = *(const bf16x8*)(Br + (size_t)(nt * 16) * 512 + k0);
    };
    auto do_mfma = [&](const GF& f) {
#pragma unroll
        for (int nt = 0; nt < 4; ++nt)
            acc[nt] = mfma_bf16(f.a, f.b[nt], acc[nt]);
    };

    GF f0, f1;
    load_f(0, f0);
#pragma unroll
    for (int k0 = 0; k0 < 512; k0 += 64) {
        if (k0 + 32 < 512) load_f(k0 + 32, f1);
        do_mfma(f0);
        if (k0 + 64 < 512) load_f(k0 + 64, f0);
        do_mfma(f1);
    }

#pragma unroll
    for (int nt = 0; nt < 4; ++nt) {
#pragma unroll
        for (int r = 0; r < 4; ++r) {
            const int row = m0 + wave * 16 + quad * 4 + r;
            const int cn  = n0 + nt * 16 + col;
            const float f = acc[nt][r];
            if (isf) ((float*)C)[(size_t)row * 1024 + cn] = f;
            else     ((bf16*)C)[(size_t)row * 1024 + cn] = (bf16)f;
        }
    }
}

// ---------------------------------------------------------------------------
// Flash causal attention: S^T operand swap + 2 strips per wave-unit.
// R14 mapping: bid = s*8 + x -> XCD x handles heads {2x, 2x+1} only (2 MB
// K+V fits per-XCD L2). Block's 4 waves = (head-lo, half) of the same q-pair
// s (heavy pairs first: pair = 127 - s). Body identical to R12.
// ---------------------------------------------------------------------------
__global__ __launch_bounds__(256) void flash_kernel(
    const bf16* __restrict__ Q, const bf16* __restrict__ K,
    const bf16* __restrict__ Vt,
    float* __restrict__ Opart, float* __restrict__ Spart)
{
    const int wave = threadIdx.x >> 6;
    const int xcd  = blockIdx.x & 7;          // round-robin XCD heuristic
    const int s    = blockIdx.x >> 3;         // 0..127, heavy-first
    const int pair = 127 - s;                 // q-pair (32 rows)
    const int bh   = 2 * xcd + (wave >> 1);   // heads {2x, 2x+1}
    const int half = wave & 1;
    const int unit = s * 16 + bh;             // == (127-pair)*16 + bh (R12 pw)
    const int wid  = unit * 2 + half;
    const int lane = threadIdx.x & 63;
    const int qc   = lane & 15;
    const int quad = lane >> 4;

    const bf16* __restrict__ Qh = Q  + (size_t)bh * (4096 * 64);
    const bf16* __restrict__ Kh = K  + (size_t)bh * (4096 * 64);
    const bf16* __restrict__ Vh = Vt + (size_t)bh * (64 * 4096);

    const int qrowA  = pair * 32;
    const int ktmax  = (2 * pair + 1) >> 2;
    const int ntiles = ktmax + 1;
    const int mid    = ntiles >> 1;
    const int k0t    = half ? mid : 0;
    const int k1t    = half ? ntiles : mid;

    bf16x8 aqA0 = *(const bf16x8*)(Qh + (size_t)(qrowA + qc) * 64 + quad * 8);
    bf16x8 aqA1 = *(const bf16x8*)(Qh + (size_t)(qrowA + qc) * 64 + 32 + quad * 8);
    bf16x8 aqB0 = *(const bf16x8*)(Qh + (size_t)(qrowA + 16 + qc) * 64 + quad * 8);
    bf16x8 aqB1 = *(const bf16x8*)(Qh + (size_t)(qrowA + 16 + qc) * 64 + 32 + quad * 8);

    f32x4 oA[4], oB[4];
    f32x4 s4A, s4B;                 // 4 independent sum chains per strip
#pragma unroll
    for (int r = 0; r < 4; ++r) { s4A[r] = 0.f; s4B[r] = 0.f; }
#pragma unroll
    for (int nt = 0; nt < 4; ++nt)
#pragma unroll
        for (int r = 0; r < 4; ++r) { oA[nt][r] = 0.f; oB[nt][r] = 0.f; }

    __shared__ __align__(16) bf16 Plds[4][2][16][72];  // per-wave, no barriers
    bf16* myPA = &Plds[wave][0][0][0];
    bf16* myPB = &Plds[wave][1][0][0];

    auto load_knt = [&](int kb, int nt, bf16x8 (&kf)[2]) {
        const bf16* kp = Kh + (size_t)(kb * 64 + nt * 16 + qc) * 64 + quad * 8;
        kf[0] = *(const bf16x8*)kp;
        kf[1] = *(const bf16x8*)(kp + 32);
    };

    if (k0t < k1t) {
        bf16x8 kc[2], kn[2];
        load_knt(k0t, 0, kc);
        for (int kb = k0t; kb < k1t; ++kb) {
            const int kbase = kb * 64;
            const bool diag = (kb == ktmax);
            bf16x8 vv[4][2];

#pragma unroll
            for (int nt = 0; nt < 4; ++nt) {
                // prefetch next K fragment (1-nt lookahead; cross-step at nt=3)
                if (nt < 3)               load_knt(kb, nt + 1, kn);
                else if (kb + 1 < k1t)    load_knt(kb + 1, 0, kn);

                // issue V load for this nt (consumed in PV; latency hides
                // under the remaining QK/exp work of this step)
                {
                    const bf16* vp = Vh + (size_t)(nt * 16 + qc) * 4096 + kbase + quad * 8;
                    vv[nt][0] = *(const bf16x8*)vp;
                    vv[nt][1] = *(const bf16x8*)(vp + 32);
                }

                // QK^T (S^T layout), both strips share the K fragment
                f32x4 sA; sA[0] = 0.f; sA[1] = 0.f; sA[2] = 0.f; sA[3] = 0.f;
                sA = mfma_bf16(kc[0], aqA0, sA);
                sA = mfma_bf16(kc[1], aqA1, sA);
                f32x4 sB; sB[0] = 0.f; sB[1] = 0.f; sB[2] = 0.f; sB[3] = 0.f;
                sB = mfma_bf16(kc[0], aqB0, sB);
                sB = mfma_bf16(kc[1], aqB1, sB);

                bf16x4v pkA, pkB;
#pragma unroll
                for (int r = 0; r < 4; ++r) {
                    float vA = sA[r];           // Q pre-scaled: no mul here
                    float vB = sB[r];
                    if (diag) {
                        const int kg = kbase + nt * 16 + quad * 4 + r;
                        if (kg > qrowA + qc)      vA = NEG_BIG;
                        if (kg > qrowA + 16 + qc) vB = NEG_BIG;
                    }
                    const float pA = __builtin_amdgcn_exp2f(vA);
                    const float pB = __builtin_amdgcn_exp2f(vB);
                    s4A[r] += pA;
                    s4B[r] += pB;
                    pkA[r] = (bf16)pA;
                    pkB[r] = (bf16)pB;
                }
                *(bf16x4v*)(myPA + qc * 72 + nt * 16 + quad * 4) = pkA;
                *(bf16x4v*)(myPB + qc * 72 + nt * 16 + quad * 4) = pkB;

                kc[0] = kn[0];
                kc[1] = kn[1];
            }

            // ---- PV for both strips (shared V frags) ----
#pragma unroll
            for (int ks = 0; ks < 2; ++ks) {
                bf16x8 apA = *(const bf16x8*)(myPA + qc * 72 + ks * 32 + quad * 8);
                bf16x8 apB = *(const bf16x8*)(myPB + qc * 72 + ks * 32 + quad * 8);
#pragma unroll
                for (int nt = 0; nt < 4; ++nt) {
                    oA[nt] = mfma_bf16(apA, vv[nt][ks], oA[nt]);
                    oB[nt] = mfma_bf16(apB, vv[nt][ks], oB[nt]);
                }
            }
        }
    }

    float sumA = (s4A[0] + s4A[1]) + (s4A[2] + s4A[3]);
    float sumB = (s4B[0] + s4B[1]) + (s4B[2] + s4B[3]);
    sumA += __shfl_xor(sumA, 16, 64);
    sumA += __shfl_xor(sumA, 32, 64);
    sumB += __shfl_xor(sumB, 16, 64);
    sumB += __shfl_xor(sumB, 32, 64);

    float* op = Opart + (size_t)wid * 2048;
#pragma unroll
    for (int nt = 0; nt < 4; ++nt)
#pragma unroll
        for (int r = 0; r < 4; ++r) {
            op[(quad * 4 + r) * 64 + nt * 16 + qc]        = oA[nt][r];
            op[1024 + (quad * 4 + r) * 64 + nt * 16 + qc] = oB[nt][r];
        }
    if (quad == 0) {
        float* sp = Spart + (size_t)wid * 32;
        sp[qc]      = sumA;
        sp[16 + qc] = sumB;
    }
}

// ---------------------------------------------------------------------------
// Combine halves: 256 threads/block, 4 units per block (grid 512).
// ---------------------------------------------------------------------------
__global__ __launch_bounds__(256) void combine_kernel(
    const float* __restrict__ Opart, const float* __restrict__ Spart,
    bf16* __restrict__ Ob)
{
    const int unit = blockIdx.x * 4 + (threadIdx.x >> 6);
    const int pair = 127 - (unit >> 4);
    const int bh   = unit & 15;
    const int c    = threadIdx.x & 63;
    const int b = bh >> 3, h = bh & 7;

    const float* o0 = Opart + (size_t)(2 * unit)     * 2048;
    const float* o1 = Opart + (size_t)(2 * unit + 1) * 2048;
    const float* s0 = Spart + (size_t)(2 * unit)     * 32;
    const float* s1 = Spart + (size_t)(2 * unit + 1) * 32;

#pragma unroll
    for (int X = 0; X < 2; ++X) {
#pragma unroll
        for (int r = 0; r < 16; ++r) {
            const float inv = 1.0f / (s0[X * 16 + r] + s1[X * 16 + r]);
            const float v = (o0[X * 1024 + r * 64 + c] + o1[X * 1024 + r * 64 + c]) * inv;
            const int t = (2 * pair + X) * 16 + r;
            Ob[((size_t)b * 4096 + t) * 512 + h * 64 + c] = (bf16)v;
        }
    }
}

extern "C" void kernel_launch(void* const* d_in, const int* in_sizes, int n_in,
                              void* d_out, int out_size, void* d_ws, size_t ws_size,
                              hipStream_t stream)
{
    (void)in_sizes; (void)n_in; (void)out_size; (void)ws_size;
    const void* x  = d_in[0];
    const void* wq = d_in[1];
    const void* wk = d_in[2];
    const void* wv = d_in[3];
    const void* wo = d_in[4];

    char* wsb = (char*)d_ws;
    bf16* xb   = (bf16*)(wsb + 0);          // [8192][512] (aliased by Ob)
    bf16* Ob   = (bf16*)(wsb + 0);
    bf16* wb   = (bf16*)(wsb + 8388608);    // [2048][512]: wq|wk|wv|wo
    bf16* wob  = wb + 3 * 262144;
    bf16* Qb   = (bf16*)(wsb + 10485760);   // [2][8][4096][64]
    bf16* Kb   = (bf16*)(wsb + 18874368);
    bf16* Vb   = (bf16*)(wsb + 27262976);   // [2][8][64][4096]
    int*  flag = (int*) (wsb + 35651584);
    float* Opart = (float*)(wsb + 35651600);   // [4096][2][16][64] fp32
    float* Spart = (float*)(wsb + 69206032);   // [4096][2][16] fp32

    const dim3 blk(256);

    sniff_dtype<<<1, blk, 0, stream>>>((const uint16_t*)x, flag);
    convert_all<<<2560, blk, 0, stream>>>(x, wq, wk, wv, wo, xb, wb, flag);

    gemm_qkv<<<dim3(24, 128), blk, 0, stream>>>(xb, wb, Qb, Kb, Vb);

    flash_kernel<<<dim3(1024), blk, 0, stream>>>(Qb, Kb, Vb, Opart, Spart);
    combine_kernel<<<dim3(512), blk, 0, stream>>>(Opart, Spart, Ob);

    gemm_out_pad<<<dim3(16, 128), blk, 0, stream>>>(Ob, wob, d_out, flag);
}

// Round 4
// 357.077 us; speedup vs baseline: 1.3306x; 1.1569x over previous
//
#include <hip/hip_runtime.h>
#include <hip/hip_bf16.h>
#include <stdint.h>

// ---------------------------------------------------------------------------
// MatryoshkaAttention: B=2, T=4096, D=1024, active_dim=512 -> H=8, hd=64.
// fp32 in/out (sniffed on-device), bf16 MFMA compute.
// R15: flash was vmem-latency bound (per-step ~10K cy vs ~800 cy issue work;
// R12 occupancy-doubling null, R14 XCD-L2 null). Fix: block = (bh, 128 q
// rows), 4 waves share K/V tiles staged ONCE into double-buffered LDS via
// global_load_lds (traffic /4, vmem instrs /4). Chunk-XOR swizzle on tiles
// (pre-swizzled global src; linear LDS dest) -> bank-balanced ds_read_b128.
// Balance by construction: each block does q-blocks (qb0, 31-qb0) with K
// ranges split so EVERY block = 33 tile-steps. Grid 512 = 2 blocks/CU.
// NO launch_bounds min arg anywhere (R6/R8: forcing VGPR caps below footprint
// -> scratch spill).
// ---------------------------------------------------------------------------

typedef __bf16 bf16;
typedef bf16  bf16x8 __attribute__((ext_vector_type(8)));
typedef bf16  bf16x4v __attribute__((ext_vector_type(4)));
typedef float f32x4  __attribute__((ext_vector_type(4)));
typedef uint32_t u32x4 __attribute__((ext_vector_type(4)));

#define SCL 0.18033688011112042f   /* 0.125 * log2(e): p = 2^(s*SCL) = e^(s/8) */
#define NEG_BIG (-30000.0f)

static __device__ __forceinline__ f32x4 mfma_bf16(bf16x8 a, bf16x8 b, f32x4 c) {
    return __builtin_amdgcn_mfma_f32_16x16x32_bf16(a, b, c, 0, 0, 0);
}

// async global->LDS, 16B per lane; LDS dest = uniform base + lane*16.
static __device__ __forceinline__ void gl_lds(const bf16* g, bf16* l) {
    __builtin_amdgcn_global_load_lds(
        (const __attribute__((address_space(1))) uint32_t*)(g),
        (__attribute__((address_space(3))) uint32_t*)(l), 16, 0, 0);
}

// ---------------------------------------------------------------------------
__global__ __launch_bounds__(256) void sniff_dtype(
    const uint16_t* __restrict__ x, int* __restrict__ flag)
{
    __shared__ int cnt;
    if (threadIdx.x == 0) cnt = 0;
    __syncthreads();
    int local = 0;
    for (int i = threadIdx.x; i < 2048; i += 256) {
        const int e = (x[i] >> 7) & 0xFF;
        if (e >= 0xC0) ++local;
    }
    if (local) atomicAdd(&cnt, local);
    __syncthreads();
    if (threadIdx.x == 0) *flag = (cnt >= 8) ? 1 : 0;
}

// ---------------------------------------------------------------------------
// One launch converts all five tensors (cols 0..511 of [rows][1024]) into
// packed bf16. Blocks 0..2047: x -> xb. Blocks 2048..2559: weights -> wb.
// ---------------------------------------------------------------------------
__global__ __launch_bounds__(256) void convert_all(
    const void* __restrict__ x,
    const void* __restrict__ wq, const void* __restrict__ wk,
    const void* __restrict__ wv, const void* __restrict__ wo,
    bf16* __restrict__ xb, bf16* __restrict__ wb,
    const int* __restrict__ flag)
{
    const int bid = blockIdx.x;
    const void* src;
    bf16* dst;
    int sub;
    if (bid < 2048) { src = x; dst = xb; sub = bid; }
    else {
        const int w = bid - 2048;
        const int wsel = w >> 7;
        src = (wsel == 0) ? wq : (wsel == 1) ? wk : (wsel == 2) ? wv : wo;
        dst = wb + (size_t)wsel * 262144;
        sub = w & 127;
    }
    const int i = (sub * 256 + threadIdx.x) * 8;
    const int r = i >> 9, c = i & 511;
    bf16x8 v;
    if (*flag) {
        const float* s = (const float*)src + (size_t)r * 1024 + c;
        f32x4 f0 = *(const f32x4*)s;
        f32x4 f1 = *(const f32x4*)(s + 4);
#pragma unroll
        for (int j = 0; j < 4; ++j) { v[j] = (bf16)f0[j]; v[4 + j] = (bf16)f1[j]; }
    } else {
        v = *(const bf16x8*)((const bf16*)src + (size_t)r * 1024 + c);
    }
    *(bf16x8*)(dst + (size_t)r * 512 + c) = v;
}

// ---------------------------------------------------------------------------
// Fused QKV NT GEMM with register ping-pong prefetch.
// A:[8192][512]; B:[1536][512] = wq|wk|wv contiguous.
// sel 0=Q head layout (pre-scaled by SCL), 1=K head layout,
// sel 2=V transposed (LDS transpose).
// ---------------------------------------------------------------------------
struct GF { bf16x8 a; bf16x8 b[4]; };

__global__ __launch_bounds__(256) void gemm_qkv(
    const bf16* __restrict__ A, const bf16* __restrict__ B,
    bf16* __restrict__ Qb, bf16* __restrict__ Kb, bf16* __restrict__ Vb)
{
    const int n0   = blockIdx.x * 64;
    const int m0   = blockIdx.y * 64;
    const int wave = threadIdx.x >> 6;
    const int lane = threadIdx.x & 63;
    const int col  = lane & 15;
    const int quad = lane >> 4;

    const bf16* __restrict__ Ar = A + (size_t)(m0 + wave * 16 + col) * 512 + quad * 8;
    const bf16* __restrict__ Br = B + (size_t)(n0 + col) * 512 + quad * 8;

    f32x4 acc[4];
#pragma unroll
    for (int nt = 0; nt < 4; ++nt)
#pragma unroll
        for (int r = 0; r < 4; ++r) acc[nt][r] = 0.0f;

    auto load_f = [&](int k0, GF& f) {
        f.a = *(const bf16x8*)(Ar + k0);
#pragma unroll
        for (int nt = 0; nt < 4; ++nt)
            f.b[nt] = *(const bf16x8*)(Br + (size_t)(nt * 16) * 512 + k0);
    };
    auto do_mfma = [&](const GF& f) {
#pragma unroll
        for (int nt = 0; nt < 4; ++nt)
            acc[nt] = mfma_bf16(f.a, f.b[nt], acc[nt]);
    };

    GF f0, f1;
    load_f(0, f0);
#pragma unroll
    for (int k0 = 0; k0 < 512; k0 += 64) {
        if (k0 + 32 < 512) load_f(k0 + 32, f1);
        do_mfma(f0);
        if (k0 + 64 < 512) load_f(k0 + 64, f0);
        do_mfma(f1);
    }

    const int sel = n0 >> 9;
    const int bb  = m0 >> 12;

    if (sel < 2) {
        bf16* __restrict__ dst = (sel == 0) ? Qb : Kb;
        const float qs = (sel == 0) ? SCL : 1.0f;   // fold softmax scale into Q
#pragma unroll
        for (int nt = 0; nt < 4; ++nt) {
#pragma unroll
            for (int r = 0; r < 4; ++r) {
                const int row = m0 + wave * 16 + quad * 4 + r;
                const int cn  = (n0 & 511) + nt * 16 + col;
                const int t = row & 4095;
                const int h = cn >> 6, d = cn & 63;
                dst[((size_t)(bb * 8 + h) * 4096 + t) * 64 + d] = (bf16)(acc[nt][r] * qs);
            }
        }
    } else {
        __shared__ __align__(16) bf16 T[64][72];
#pragma unroll
        for (int nt = 0; nt < 4; ++nt)
#pragma unroll
            for (int r = 0; r < 4; ++r)
                T[wave * 16 + quad * 4 + r][nt * 16 + col] = (bf16)acc[nt][r];
        __syncthreads();

        const int h0 = (n0 - 1024) >> 6;
        const int d  = threadIdx.x >> 2;
        const int tp = (threadIdx.x & 3) * 16;
        bf16 vals[16];
#pragma unroll
        for (int i = 0; i < 16; ++i) vals[i] = T[tp + i][d];
        bf16* dst = Vb + ((size_t)(bb * 8 + h0) * 64 + d) * 4096 + (m0 & 4095) + tp;
        *(bf16x8*)dst       = *(bf16x8*)&vals[0];
        *(bf16x8*)(dst + 8) = *(bf16x8*)&vals[8];
    }
}

// ---------------------------------------------------------------------------
// Out-projection NT GEMM + fused pad, with ping-pong prefetch.
// grid (16,128). n0<512: C = A*wo^T; n0>=512: zero-fill tile.
// ---------------------------------------------------------------------------
__global__ __launch_bounds__(256) void gemm_out_pad(
    const bf16* __restrict__ A, const bf16* __restrict__ B, void* __restrict__ C,
    const int* __restrict__ flag)
{
    const int n0   = blockIdx.x * 64;
    const int m0   = blockIdx.y * 64;
    const int isf  = *flag;

    if (n0 >= 512) {
        const int row = m0 + (threadIdx.x >> 2);
        const int c0  = n0 + (threadIdx.x & 3) * 16;
        if (isf) {
            float* p = (float*)C + (size_t)row * 1024 + c0;
            f32x4 z; z[0] = 0.f; z[1] = 0.f; z[2] = 0.f; z[3] = 0.f;
#pragma unroll
            for (int j = 0; j < 4; ++j) *(f32x4*)(p + j * 4) = z;
        } else {
            bf16* p = (bf16*)C + (size_t)row * 1024 + c0;
            u32x4 z; z[0] = 0u; z[1] = 0u; z[2] = 0u; z[3] = 0u;
            *(u32x4*)p = z; *(u32x4*)(p + 8) = z;
        }
        return;
    }

    const int wave = threadIdx.x >> 6;
    const int lane = threadIdx.x & 63;
    const int col  = lane & 15;
    const int quad = lane >> 4;

    const bf16* __restrict__ Ar = A + (size_t)(m0 + wave * 16 + col) * 512 + quad * 8;
    const bf16* __restrict__ Br = B + (size_t)(n0 + col) * 512 + quad * 8;

    f32x4 acc[4];
#pragma unroll
    for (int nt = 0; nt < 4; ++nt)
#pragma unroll
        for (int r = 0; r < 4; ++r) acc[nt][r] = 0.0f;

    auto load_f = [&](int k0, GF& f) {
        f.a = *(const bf16x8*)(Ar + k0);
#pragma unroll
        for (int nt = 0; nt < 4; ++nt)
            f.b[nt] = *(const bf16x8*)(Br + (size_t)(nt * 16) * 512 + k0);
    };
    auto do_mfma = [&](const GF& f) {
#pragma unroll
        for (int nt = 0; nt < 4; ++nt)
            acc[nt] = mfma_bf16(f.a, f.b[nt], acc[nt]);
    };

    GF f0, f1;
    load_f(0, f0);
#pragma unroll
    for (int k0 = 0; k0 < 512; k0 += 64) {
        if (k0 + 32 < 512) load_f(k0 + 32, f1);
        do_mfma(f0);
        if (k0 + 64 < 512) load_f(k0 + 64, f0);
        do_mfma(f1);
    }

#pragma unroll
    for (int nt = 0; nt < 4; ++nt) {
#pragma unroll
        for (int r = 0; r < 4; ++r) {
            const int row = m0 + wave * 16 + quad * 4 + r;
            const int cn  = n0 + nt * 16 + col;
            const float f = acc[nt][r];
            if (isf) ((float*)C)[(size_t)row * 1024 + cn] = f;
            else     ((bf16*)C)[(size_t)row * 1024 + cn] = (bf16)f;
        }
    }
}

// ---------------------------------------------------------------------------
// Flash causal attention, LDS-shared K/V tiles.
// Block = (bh, qb0, s): processes q-block qb0 (rows qb0*128..+128) with
// K-tiles [s? qb0+1 : 0, s? 2qb0+2 : qb0+1), then q-block 31-qb0 with
// K-tiles [s? 0 : 32-qb0, s? 32-qb0 : 64-2qb0). Every block = 33 tile-steps.
// Waves 0..3 own 32 q-rows each (2 strips of 16, S^T operand swap as before).
// K/V tiles double-buffered in LDS with chunk-XOR swizzle (src pre-swizzled,
// global_load_lds writes linearly). Partial pw = (qb*16+bh)*2 + s.
// ---------------------------------------------------------------------------
__global__ __launch_bounds__(256) void flash_kernel(
    const bf16* __restrict__ Q, const bf16* __restrict__ K,
    const bf16* __restrict__ Vt,
    float* __restrict__ Opart, float* __restrict__ Spart)
{
    const int wave = threadIdx.x >> 6;
    const int lane = threadIdx.x & 63;
    const int qc   = lane & 15;
    const int quad = lane >> 4;

    const int bh  = blockIdx.x & 15;
    const int qb0 = (blockIdx.x >> 4) & 15;
    const int s   = blockIdx.x >> 8;          // 0..1

    const bf16* __restrict__ Qh = Q  + (size_t)bh * (4096 * 64);
    const bf16* __restrict__ Kh = K  + (size_t)bh * (4096 * 64);
    const bf16* __restrict__ Vh = Vt + (size_t)bh * (64 * 4096);

    __shared__ __align__(16) bf16 Ksh[2][64][64];
    __shared__ __align__(16) bf16 Vsh[2][64][64];
    __shared__ __align__(16) bf16 Plds[4][2][16][72];  // per-wave, no barriers
    bf16* myPA = &Plds[wave][0][0][0];
    bf16* myPB = &Plds[wave][1][0][0];

    // stage tile kb into buf: each wave stages K rows [16w,16w+16) and V
    // d-rows [16w,16w+16), 2 x 1KB issues each. LDS linear; global src
    // pre-swizzled: LDS[r][chunk] = G[r][chunk ^ (r&7)] (chunk = 8 elems).
    auto stage = [&](int kb, int buf) {
        const int rr = lane >> 3, cc = lane & 7;    // rr 0..7, cc 0..7
#pragma unroll
        for (int j = 0; j < 2; ++j) {
            const int r0 = wave * 16 + j * 8;
            const int r  = r0 + rr;
            const int cs = (cc ^ rr) * 8;           // r&7 == rr (r0 % 8 == 0)
            gl_lds(Kh + (size_t)(kb * 64 + r) * 64 + cs, &Ksh[buf][r0][0]);
            gl_lds(Vh + (size_t)r * 4096 + kb * 64 + cs, &Vsh[buf][r0][0]);
        }
    };

    for (int chunk = 0; chunk < 2; ++chunk) {
        const int qb = chunk ? (31 - qb0) : qb0;
        int k0, k1;
        if (chunk == 0) { k0 = s ? (qb0 + 1) : 0;   k1 = s ? (2 * qb0 + 2) : (qb0 + 1); }
        else            { k0 = s ? 0 : (32 - qb0);  k1 = s ? (32 - qb0) : (64 - 2 * qb0); }

        const int qrow   = qb * 128 + wave * 32;    // this wave's 32-row band
        const int ktmaxw = 2 * qb + (wave >> 1);    // wave's diagonal tile

        bf16x8 aqA0 = *(const bf16x8*)(Qh + (size_t)(qrow + qc) * 64 + quad * 8);
        bf16x8 aqA1 = *(const bf16x8*)(Qh + (size_t)(qrow + qc) * 64 + 32 + quad * 8);
        bf16x8 aqB0 = *(const bf16x8*)(Qh + (size_t)(qrow + 16 + qc) * 64 + quad * 8);
        bf16x8 aqB1 = *(const bf16x8*)(Qh + (size_t)(qrow + 16 + qc) * 64 + 32 + quad * 8);

        f32x4 oA[4], oB[4];
        f32x4 s4A, s4B;
#pragma unroll
        for (int r = 0; r < 4; ++r) { s4A[r] = 0.f; s4B[r] = 0.f; }
#pragma unroll
        for (int nt = 0; nt < 4; ++nt)
#pragma unroll
            for (int r = 0; r < 4; ++r) { oA[nt][r] = 0.f; oB[nt][r] = 0.f; }

        stage(k0, k0 & 1);
        asm volatile("s_waitcnt vmcnt(0)" ::: "memory");
        __syncthreads();

        for (int kb = k0; kb < k1; ++kb) {
            const int buf = kb & 1;
            if (kb + 1 < k1) stage(kb + 1, (kb + 1) & 1);

            if (kb <= ktmaxw) {
                const int kbase = kb * 64;
                const bool diag = (kb == ktmaxw);
                const int h = qc & 7;

                // ---- QK^T + exp + pack to P-LDS ----
#pragma unroll
                for (int nt = 0; nt < 4; ++nt) {
                    const int r = nt * 16 + qc;
                    bf16x8 kf0 = *(const bf16x8*)&Ksh[buf][r][(quad ^ h) * 8];
                    bf16x8 kf1 = *(const bf16x8*)&Ksh[buf][r][((quad + 4) ^ h) * 8];

                    f32x4 sA; sA[0] = 0.f; sA[1] = 0.f; sA[2] = 0.f; sA[3] = 0.f;
                    sA = mfma_bf16(kf0, aqA0, sA);
                    sA = mfma_bf16(kf1, aqA1, sA);
                    f32x4 sB; sB[0] = 0.f; sB[1] = 0.f; sB[2] = 0.f; sB[3] = 0.f;
                    sB = mfma_bf16(kf0, aqB0, sB);
                    sB = mfma_bf16(kf1, aqB1, sB);

                    bf16x4v pkA, pkB;
#pragma unroll
                    for (int r2 = 0; r2 < 4; ++r2) {
                        float vA = sA[r2];          // Q pre-scaled: no mul here
                        float vB = sB[r2];
                        if (diag) {
                            const int kg = kbase + nt * 16 + quad * 4 + r2;
                            if (kg > qrow + qc)      vA = NEG_BIG;
                            if (kg > qrow + 16 + qc) vB = NEG_BIG;
                        }
                        const float pA = __builtin_amdgcn_exp2f(vA);
                        const float pB = __builtin_amdgcn_exp2f(vB);
                        s4A[r2] += pA;
                        s4B[r2] += pB;
                        pkA[r2] = (bf16)pA;
                        pkB[r2] = (bf16)pB;
                    }
                    *(bf16x4v*)(myPA + qc * 72 + nt * 16 + quad * 4) = pkA;
                    *(bf16x4v*)(myPB + qc * 72 + nt * 16 + quad * 4) = pkB;
                }

                // ---- PV for both strips, V from LDS ----
#pragma unroll
                for (int ks = 0; ks < 2; ++ks) {
                    bf16x8 apA = *(const bf16x8*)(myPA + qc * 72 + ks * 32 + quad * 8);
                    bf16x8 apB = *(const bf16x8*)(myPB + qc * 72 + ks * 32 + quad * 8);
#pragma unroll
                    for (int nt = 0; nt < 4; ++nt) {
                        const int d = nt * 16 + qc;
                        bf16x8 vf = *(const bf16x8*)&Vsh[buf][d][((4 * ks + quad) ^ h) * 8];
                        oA[nt] = mfma_bf16(apA, vf, oA[nt]);
                        oB[nt] = mfma_bf16(apB, vf, oB[nt]);
                    }
                }
            }

            asm volatile("s_waitcnt vmcnt(0)" ::: "memory");
            __syncthreads();
        }

        // ---- epilogue: write partial (qb, s) ----
        float sumA = (s4A[0] + s4A[1]) + (s4A[2] + s4A[3]);
        float sumB = (s4B[0] + s4B[1]) + (s4B[2] + s4B[3]);
        sumA += __shfl_xor(sumA, 16, 64);
        sumA += __shfl_xor(sumA, 32, 64);
        sumB += __shfl_xor(sumB, 16, 64);
        sumB += __shfl_xor(sumB, 32, 64);

        const int pw = (qb * 16 + bh) * 2 + s;
        float* op = Opart + (size_t)pw * 8192 + (size_t)(wave * 32) * 64;
#pragma unroll
        for (int nt = 0; nt < 4; ++nt)
#pragma unroll
            for (int r = 0; r < 4; ++r) {
                op[(quad * 4 + r) * 64 + nt * 16 + qc]        = oA[nt][r];
                op[1024 + (quad * 4 + r) * 64 + nt * 16 + qc] = oB[nt][r];
            }
        if (quad == 0) {
            float* sp = Spart + (size_t)pw * 128 + wave * 32;
            sp[qc]      = sumA;
            sp[16 + qc] = sumB;
        }
    }
}

// ---------------------------------------------------------------------------
// Combine: 512 units (qb*16+bh) x 128 rows; sum 2 partials, normalize.
// Grid 512 x 256 thr: col = tid&63, row group = tid>>6 (32 rows each).
// ---------------------------------------------------------------------------
__global__ __launch_bounds__(256) void combine_kernel(
    const float* __restrict__ Opart, const float* __restrict__ Spart,
    bf16* __restrict__ Ob)
{
    const int u  = blockIdx.x;            // 0..511
    const int qb = u >> 4;
    const int bh = u & 15;
    const int c  = threadIdx.x & 63;
    const int g  = threadIdx.x >> 6;
    const int b = bh >> 3, h = bh & 7;

    const float* o0 = Opart + (size_t)(u * 2) * 8192;
    const float* o1 = o0 + 8192;
    const float* s0 = Spart + (size_t)(u * 2) * 128;
    const float* s1 = s0 + 128;

#pragma unroll 4
    for (int rr = 0; rr < 32; ++rr) {
        const int row = g * 32 + rr;
        const float inv = 1.0f / (s0[row] + s1[row]);
        const float v = (o0[row * 64 + c] + o1[row * 64 + c]) * inv;
        const int t = qb * 128 + row;
        Ob[((size_t)b * 4096 + t) * 512 + h * 64 + c] = (bf16)v;
    }
}

extern "C" void kernel_launch(void* const* d_in, const int* in_sizes, int n_in,
                              void* d_out, int out_size, void* d_ws, size_t ws_size,
                              hipStream_t stream)
{
    (void)in_sizes; (void)n_in; (void)out_size; (void)ws_size;
    const void* x  = d_in[0];
    const void* wq = d_in[1];
    const void* wk = d_in[2];
    const void* wv = d_in[3];
    const void* wo = d_in[4];

    char* wsb = (char*)d_ws;
    bf16* xb   = (bf16*)(wsb + 0);          // [8192][512] (aliased by Ob)
    bf16* Ob   = (bf16*)(wsb + 0);
    bf16* wb   = (bf16*)(wsb + 8388608);    // [2048][512]: wq|wk|wv|wo
    bf16* wob  = wb + 3 * 262144;
    bf16* Qb   = (bf16*)(wsb + 10485760);   // [2][8][4096][64]
    bf16* Kb   = (bf16*)(wsb + 18874368);
    bf16* Vb   = (bf16*)(wsb + 27262976);   // [2][8][64][4096]
    int*  flag = (int*) (wsb + 35651584);
    float* Opart = (float*)(wsb + 35651600);   // [1024 pw][128][64] fp32 = 33.5MB
    float* Spart = (float*)(wsb + 69206032);   // [1024 pw][128] fp32 = 512KB

    const dim3 blk(256);

    sniff_dtype<<<1, blk, 0, stream>>>((const uint16_t*)x, flag);
    convert_all<<<2560, blk, 0, stream>>>(x, wq, wk, wv, wo, xb, wb, flag);

    gemm_qkv<<<dim3(24, 128), blk, 0, stream>>>(xb, wb, Qb, Kb, Vb);

    flash_kernel<<<dim3(512), blk, 0, stream>>>(Qb, Kb, Vb, Opart, Spart);
    combine_kernel<<<dim3(512), blk, 0, stream>>>(Opart, Spart, Ob);

    gemm_out_pad<<<dim3(16, 128), blk, 0, stream>>>(Ob, wob, d_out, flag);
}